// Round 1
// 552.162 us; speedup vs baseline: 1.0058x; 1.0058x over previous
//
#include <hip/hip_runtime.h>

// Dense GEMM: C[M,N] = x[M,K] @ W[K,N] + bias[N], f32 in/out, bf16 MFMA compute.
// R4: LDS-tiled W-transpose in prep (coalesced 128B-row writes instead of
//     16B writes strided 8KB — prep was ~228us vs ~46us roofline).
//     GEMM unchanged (840 TF, at the 128^2/2-barrier structure ceiling).

#define MDIM 8192
#define NDIM 4096
#define KDIM 4096
#define BM 128
#define BN 128
#define BK 64

typedef __bf16 bf16x8 __attribute__((ext_vector_type(8)));
typedef float f32x4 __attribute__((ext_vector_type(4)));
typedef unsigned short u16x8 __attribute__((ext_vector_type(8)));

__device__ __forceinline__ unsigned short f32_to_bf16(float f) {
  union { float f; unsigned int u; } v; v.f = f;
  unsigned int r = 0x7FFFu + ((v.u >> 16) & 1u);  // round-to-nearest-even
  return (unsigned short)((v.u + r) >> 16);
}

// ---- fused pre-pass ------------------------------------------------------
// blocks [0, CVT_BLOCKS)             : convert x f32 -> bf16 (streaming)
// blocks [CVT_BLOCKS, +4096)         : transpose W [K][N] f32 -> Wt [N][K] bf16
//                                      via 64x64 LDS tile, coalesced both sides
#define CVT_BLOCKS 16384
__global__ __launch_bounds__(256) void prep_kernel(
    const float* __restrict__ x, const float* __restrict__ W,
    unsigned short* __restrict__ Xbf, unsigned short* __restrict__ Wt) {
  // 64 x 64 bf16 tile, stored transposed: tile[n_local][k_local].
  // Row stride 72 elems = 144 B = 9*16 B -> u16x8 reads stay 16B-aligned,
  // and the odd multiple of 16 breaks the worst same-bank column patterns.
  __shared__ __align__(16) unsigned short tile[64][72];

  const int bid = blockIdx.x;
  const int t = threadIdx.x;
  if (bid < CVT_BLOCKS) {
    const int i = (bid * 256 + t) * 8;
    float4 a = *(const float4*)(x + i);
    float4 b = *(const float4*)(x + i + 4);
    union { unsigned short s[8]; uint4 v; } o;
    o.s[0] = f32_to_bf16(a.x); o.s[1] = f32_to_bf16(a.y);
    o.s[2] = f32_to_bf16(a.z); o.s[3] = f32_to_bf16(a.w);
    o.s[4] = f32_to_bf16(b.x); o.s[5] = f32_to_bf16(b.y);
    o.s[6] = f32_to_bf16(b.z); o.s[7] = f32_to_bf16(b.w);
    *(uint4*)(Xbf + i) = o.v;
  } else {
    const int tb = bid - CVT_BLOCKS;      // 4096 blocks: 64 n-tiles x 64 k-tiles
    const int n0 = (tb & 63) * 64;
    const int k0 = (tb >> 6) * 64;

    // Read phase: 4 passes x (16 k-rows x 64 n). float4 per lane -> each
    // 16-lane group reads one contiguous 256B row segment. Store transposed
    // into LDS (scalar 2B writes; conflicts irrelevant vs global traffic).
#pragma unroll
    for (int p = 0; p < 4; p++) {
      const int kk = p * 16 + (t >> 4);
      const int nl = (t & 15) * 4;
      float4 v = *(const float4*)(W + (size_t)(k0 + kk) * NDIM + n0 + nl);
      tile[nl + 0][kk] = f32_to_bf16(v.x);
      tile[nl + 1][kk] = f32_to_bf16(v.y);
      tile[nl + 2][kk] = f32_to_bf16(v.z);
      tile[nl + 3][kk] = f32_to_bf16(v.w);
    }
    __syncthreads();

    // Write phase: 2 passes x (32 n-rows x 64 k). u16x8 per lane -> each
    // 8-lane group writes one contiguous 128B row of Wt. Fully coalesced.
#pragma unroll
    for (int q = 0; q < 2; q++) {
      const int nl = q * 32 + (t >> 3);
      const int kl = (t & 7) * 8;
      *(u16x8*)(Wt + (size_t)(n0 + nl) * KDIM + k0 + kl) =
          *(const u16x8*)(&tile[nl][kl]);
    }
  }
}

// ---- GEMM: C = A(bf16, MxK) * Bt(bf16, NxK)^T + bias, f32 out ------------
#define GLD_TO_LDS(g, l)                                                      \
  __builtin_amdgcn_global_load_lds(                                           \
      (const __attribute__((address_space(1))) void*)(g),                     \
      (__attribute__((address_space(3))) void*)(l), 16, 0, 0)

__global__ __launch_bounds__(256) void gemm_bf16_kernel(
    const unsigned short* __restrict__ A,   // M x K bf16
    const unsigned short* __restrict__ Bt,  // N x K bf16
    const float* __restrict__ bias,
    float* __restrict__ C) {
  // Rows of 64 bf16 (8 chunks of 16B). Chunk slot s' holds global chunk
  // s = s' ^ (row&7)  -> ds_read_b128 lanes spread 8/bank-group (full rate),
  // and global_load_lds stays lane-contiguous (base + lane*16).
  __shared__ __align__(16) unsigned short As[BM * BK];  // 16 KB
  __shared__ __align__(16) unsigned short Bs[BN * BK];  // 16 KB

  const int tid  = threadIdx.x;
  const int wave = tid >> 6;
  const int lane = tid & 63;
  const int lr   = lane & 15;
  const int quad = lane >> 4;

  const int bm0 = blockIdx.y * BM;
  const int bn0 = blockIdx.x * BN;

  // Staging: wave w stages rows [w*32, w*32+32), 4 instrs x (8 rows x 128B).
  // lane -> row = i*8 + (lane>>3), slot s' = lane&7 -> global chunk s'^(row&7).
  const int stRow = wave * 32 + (lane >> 3);
  const int stSeg = ((lane & 7) ^ ((lane >> 3) & 7)) * 8;  // elements
  const unsigned short* gA0 = A  + (size_t)(bm0 + stRow) * KDIM + stSeg;
  const unsigned short* gA1 = gA0 + 8 * KDIM;
  const unsigned short* gA2 = gA0 + 16 * KDIM;
  const unsigned short* gA3 = gA0 + 24 * KDIM;
  const unsigned short* gB0 = Bt + (size_t)(bn0 + stRow) * KDIM + stSeg;
  const unsigned short* gB1 = gB0 + 8 * KDIM;
  const unsigned short* gB2 = gB0 + 16 * KDIM;
  const unsigned short* gB3 = gB0 + 24 * KDIM;
  unsigned short* lA = As + wave * 2048;   // wave-uniform LDS bases
  unsigned short* lB = Bs + wave * 2048;

  // Wave computes 64x64: 4x4 frags of 16x16x32, two k-halves per BK=64 slab.
  const int wm = (wave >> 1) * 64;
  const int wn = (wave & 1) * 64;
  const int xr = lr & 7;
  // frag (i, half h): addr = (wm+lr)*64 + i*1024 + ((h*4+quad)^xr)*8
  const int slot0 = (quad ^ xr) * 8;            // h=0
  const int slot1 = ((4 + quad) ^ xr) * 8;      // h=1
  const unsigned short* aRow = As + (wm + lr) * BK;
  const unsigned short* bRow = Bs + (wn + lr) * BK;

  f32x4 acc[4][4] = {};

  for (int k0 = 0; k0 < KDIM; k0 += BK) {
    GLD_TO_LDS(gA0, lA);
    GLD_TO_LDS(gA1, lA + 512);
    GLD_TO_LDS(gA2, lA + 1024);
    GLD_TO_LDS(gA3, lA + 1536);
    GLD_TO_LDS(gB0, lB);
    GLD_TO_LDS(gB1, lB + 512);
    GLD_TO_LDS(gB2, lB + 1024);
    GLD_TO_LDS(gB3, lB + 1536);
    gA0 += BK; gA1 += BK; gA2 += BK; gA3 += BK;
    gB0 += BK; gB1 += BK; gB2 += BK; gB3 += BK;
    __syncthreads();

    // half 0 (k = 0..31 of slab)
    {
      bf16x8 af[4], bfv[4];
#pragma unroll
      for (int i = 0; i < 4; i++) {
        af[i]  = *(const bf16x8*)(aRow + i * 16 * BK + slot0);
        bfv[i] = *(const bf16x8*)(bRow + i * 16 * BK + slot0);
      }
#pragma unroll
      for (int mi = 0; mi < 4; mi++)
#pragma unroll
        for (int ni = 0; ni < 4; ni++)
          acc[mi][ni] = __builtin_amdgcn_mfma_f32_16x16x32_bf16(
              af[mi], bfv[ni], acc[mi][ni], 0, 0, 0);
    }
    // half 1 (k = 32..63 of slab)
    {
      bf16x8 af[4], bfv[4];
#pragma unroll
      for (int i = 0; i < 4; i++) {
        af[i]  = *(const bf16x8*)(aRow + i * 16 * BK + slot1);
        bfv[i] = *(const bf16x8*)(bRow + i * 16 * BK + slot1);
      }
#pragma unroll
      for (int mi = 0; mi < 4; mi++)
#pragma unroll
        for (int ni = 0; ni < 4; ni++)
          acc[mi][ni] = __builtin_amdgcn_mfma_f32_16x16x32_bf16(
              af[mi], bfv[ni], acc[mi][ni], 0, 0, 0);
    }
    __syncthreads();
  }

  // Epilogue: C/D layout col = lane&15, row = quad*4 + reg  [m89/m91]
  const int om = bm0 + wm + quad * 4;
  const int on = bn0 + wn + lr;
#pragma unroll
  for (int ni = 0; ni < 4; ni++) {
    float bv = bias[on + ni * 16];
#pragma unroll
    for (int mi = 0; mi < 4; mi++) {
      f32x4 v = acc[mi][ni];
#pragma unroll
      for (int r = 0; r < 4; r++) {
        C[(size_t)(om + mi * 16 + r) * NDIM + (on + ni * 16)] = v[r] + bv;
      }
    }
  }
}

extern "C" void kernel_launch(void* const* d_in, const int* in_sizes, int n_in,
                              void* d_out, int out_size, void* d_ws, size_t ws_size,
                              hipStream_t stream) {
  const float* x    = (const float*)d_in[0];  // 8192 x 4096
  const float* w    = (const float*)d_in[1];  // 4096 x 4096 ([k][n])
  const float* bias = (const float*)d_in[2];  // 4096
  float* out = (float*)d_out;

  unsigned short* Xbf = (unsigned short*)d_ws;  // 64 MB
  unsigned short* Wt  = (unsigned short*)((char*)d_ws + (size_t)MDIM * KDIM * 2);  // 32 MB

  prep_kernel<<<CVT_BLOCKS + 4096, 256, 0, stream>>>(x, w, Xbf, Wt);
  gemm_bf16_kernel<<<dim3(NDIM / BN, MDIM / BM), 256, 0, stream>>>(Xbf, Wt, bias, out);
}

// Round 2
// 508.618 us; speedup vs baseline: 1.0919x; 1.0856x over previous
//
#include <hip/hip_runtime.h>

// Dense GEMM: C[M,N] = x[M,K] @ W[K,N] + bias[N], f32 in/out, bf16 MFMA compute.
// R5: 256x256 8-phase GEMM (T3+T4 counted vmcnt(6) + T5 setprio), ring-4
//     k-half LDS slots [256][32] with (row>>1)&3 chunk swizzle (2-way, free).
//     Stage stream: half-tile g issued at phase g-5; vmcnt(6) every phase end.
//     Prep unchanged.

#define MDIM 8192
#define NDIM 4096
#define KDIM 4096
#define BM 256
#define BN 256
#define BK 64
#define NKT (KDIM / BK)   // 64 K-tiles
#define NH  (KDIM / 32)   // 128 k-half tiles per operand

typedef __bf16 bf16x8 __attribute__((ext_vector_type(8)));
typedef float f32x4 __attribute__((ext_vector_type(4)));
typedef unsigned short u16x8 __attribute__((ext_vector_type(8)));

__device__ __forceinline__ unsigned short f32_to_bf16(float f) {
  union { float f; unsigned int u; } v; v.f = f;
  unsigned int r = 0x7FFFu + ((v.u >> 16) & 1u);  // round-to-nearest-even
  return (unsigned short)((v.u + r) >> 16);
}

// ---- fused pre-pass ------------------------------------------------------
#define CVT_BLOCKS 16384
__global__ __launch_bounds__(256) void prep_kernel(
    const float* __restrict__ x, const float* __restrict__ W,
    unsigned short* __restrict__ Xbf, unsigned short* __restrict__ Wt) {
  __shared__ __align__(16) unsigned short tile[64][72];

  const int bid = blockIdx.x;
  const int t = threadIdx.x;
  if (bid < CVT_BLOCKS) {
    const int i = (bid * 256 + t) * 8;
    float4 a = *(const float4*)(x + i);
    float4 b = *(const float4*)(x + i + 4);
    union { unsigned short s[8]; uint4 v; } o;
    o.s[0] = f32_to_bf16(a.x); o.s[1] = f32_to_bf16(a.y);
    o.s[2] = f32_to_bf16(a.z); o.s[3] = f32_to_bf16(a.w);
    o.s[4] = f32_to_bf16(b.x); o.s[5] = f32_to_bf16(b.y);
    o.s[6] = f32_to_bf16(b.z); o.s[7] = f32_to_bf16(b.w);
    *(uint4*)(Xbf + i) = o.v;
  } else {
    const int tb = bid - CVT_BLOCKS;      // 4096 blocks: 64 n-tiles x 64 k-tiles
    const int n0 = (tb & 63) * 64;
    const int k0 = (tb >> 6) * 64;
#pragma unroll
    for (int p = 0; p < 4; p++) {
      const int kk = p * 16 + (t >> 4);
      const int nl = (t & 15) * 4;
      float4 v = *(const float4*)(W + (size_t)(k0 + kk) * NDIM + n0 + nl);
      tile[nl + 0][kk] = f32_to_bf16(v.x);
      tile[nl + 1][kk] = f32_to_bf16(v.y);
      tile[nl + 2][kk] = f32_to_bf16(v.z);
      tile[nl + 3][kk] = f32_to_bf16(v.w);
    }
    __syncthreads();
#pragma unroll
    for (int q = 0; q < 2; q++) {
      const int nl = q * 32 + (t >> 3);
      const int kl = (t & 7) * 8;
      *(u16x8*)(Wt + (size_t)(n0 + nl) * KDIM + k0 + kl) =
          *(const u16x8*)(&tile[nl][kl]);
    }
  }
}

// ---- GEMM ---------------------------------------------------------------
#define GLD_TO_LDS(g, l)                                                      \
  __builtin_amdgcn_global_load_lds(                                           \
      (const __attribute__((address_space(1))) void*)(g),                     \
      (__attribute__((address_space(3))) void*)(l), 16, 0, 0)

__global__ __launch_bounds__(512, 2) void gemm_bf16_kernel(
    const unsigned short* __restrict__ A,   // M x K bf16
    const unsigned short* __restrict__ Bt,  // N x K bf16
    const float* __restrict__ bias,
    float* __restrict__ C) {
  // 4 ring slots per operand; slot = k-half tile [256 rows][32 k] bf16 (16 KB).
  // Within a row (64 B = 4 chunks of 16 B), LDS chunk c' holds global chunk
  // c = c' ^ ((row>>1)&3): ds_read_b128 lanes land 2/bank-cell (free).
  __shared__ __align__(16) unsigned short As[4 * 8192];  // 64 KB
  __shared__ __align__(16) unsigned short Bs[4 * 8192];  // 64 KB

  const int tid  = threadIdx.x;
  const int w    = tid >> 6;
  const int lane = tid & 63;

  // XCD-aware swizzle (nwg=512, 512%8==0): each XCD gets 64 contiguous wgs
  // = 2 bn x 32 bm -> B-panel (2 MB) reused 32x from its private L2.
  const int wg  = (blockIdx.x & 7) * 64 + (blockIdx.x >> 3);
  const int bm0 = (wg & 31) * BM;
  const int bn0 = (wg >> 5) * BN;

  // ---- staging map: wave w writes slot bytes [w*2KB, +2KB) as 2 x 1KB ----
  // linear LDS elem = w*1024 + j*512 + lane*8 -> row = w*32+j*16+(lane>>2),
  // chunk' = lane&3; source chunk = chunk' ^ ((row>>1)&3) = (lane&3)^((lane>>3)&3)
  const int stR = w * 32 + (lane >> 2);
  const int cSw = ((lane & 3) ^ ((lane >> 3) & 3)) * 8;
  const unsigned short* sA0 = A  + (size_t)(bm0 + stR) * KDIM + cSw;
  const unsigned short* sA1 = sA0 + (size_t)16 * KDIM;
  const unsigned short* sB0 = Bt + (size_t)(bn0 + stR) * KDIM + cSw;
  const unsigned short* sB1 = sB0 + (size_t)16 * KDIM;
  unsigned short* ldsA = As + w * 1024;   // + slot*8192 (+512 for j=1)
  unsigned short* ldsB = Bs + w * 1024;

  // ---- compute map: wave (wr,wc) owns 128x64 at (wr*128, wc*64) ----------
  const int wr = w >> 2;
  const int wc = w & 3;
  // frag read: lane row = base+(lane&15), k-chunk = lane>>4, swizzled:
  const int pa = (lane & 15) * 32 + (((lane >> 4) ^ ((lane >> 1) & 3))) * 8;
  const unsigned short* aBase = As + (wr * 128) * 32 + pa;  // +slot +mh*2048 +fm*512
  const unsigned short* bBase = Bs + (wc * 64) * 32 + pa;   // +slot +fn*512

  f32x4 acc[8][4] = {};

  // stage half-tile h of operand (0=A,1=B): exactly 2 vmem ops per wave.
  // Tail (h>=NH): re-stage k-half 0 into the (never-again-read) slot so the
  // per-phase vmcnt op count stays exact.
  auto stage = [&](int h, int isB) {
    const int koff = (h < NH) ? h * 32 : 0;
    const int sb = (h & 3) * 8192;
    if (isB) {
      GLD_TO_LDS(sB0 + koff, ldsB + sb);
      GLD_TO_LDS(sB1 + koff, ldsB + sb + 512);
    } else {
      GLD_TO_LDS(sA0 + koff, ldsA + sb);
      GLD_TO_LDS(sA1 + koff, ldsA + sb + 512);
    }
  };

  // Prologue: issue stream g=0..4 = A(h0),B(h0),A(h1),B(h1),A(h2); wait for
  // h0 (oldest 4 ops of 10) before phase 0.
  stage(0, 0); stage(0, 1); stage(1, 0); stage(1, 1); stage(2, 0);
  asm volatile("s_waitcnt vmcnt(6)" ::: "memory");
  __builtin_amdgcn_sched_barrier(0);
  __builtin_amdgcn_s_barrier();
  __builtin_amdgcn_sched_barrier(0);

  for (int kt = 0; kt < NKT; ++kt) {
    const int s0 = ((2 * kt) & 3) * 8192;
    const int s1 = ((2 * kt + 1) & 3) * 8192;
    bf16x8 aF[4], bF[4];

#define PHASE(SLOT, MH, ACC0, LOADB, STH, STB)                                \
    {                                                                         \
      _Pragma("unroll")                                                       \
      for (int f = 0; f < 4; ++f)                                             \
        aF[f] = *(const bf16x8*)(aBase + (SLOT) + (MH)*2048 + f * 512);       \
      if (LOADB) {                                                            \
        _Pragma("unroll")                                                     \
        for (int f = 0; f < 4; ++f)                                           \
          bF[f] = *(const bf16x8*)(bBase + (SLOT) + f * 512);                 \
      }                                                                       \
      stage((STH), (STB));                                                    \
      __builtin_amdgcn_s_barrier();                                           \
      __builtin_amdgcn_sched_barrier(0);                                      \
      __builtin_amdgcn_s_setprio(1);                                          \
      _Pragma("unroll")                                                       \
      for (int m = 0; m < 4; ++m)                                             \
        _Pragma("unroll")                                                     \
        for (int n = 0; n < 4; ++n)                                           \
          acc[(ACC0) + m][n] = __builtin_amdgcn_mfma_f32_16x16x32_bf16(       \
              aF[m], bF[n], acc[(ACC0) + m][n], 0, 0, 0);                     \
      __builtin_amdgcn_s_setprio(0);                                          \
      asm volatile("s_waitcnt vmcnt(6)" ::: "memory");                        \
      __builtin_amdgcn_sched_barrier(0);                                      \
      __builtin_amdgcn_s_barrier();                                           \
      __builtin_amdgcn_sched_barrier(0);                                      \
    }

    // phase 0: (kh0, mh0)  stages g=4kt+5 = B(2kt+2)
    PHASE(s0, 0, 0, 1, 2 * kt + 2, 1)
    // phase 1: (kh0, mh1)  stages g=4kt+6 = A(2kt+3)
    PHASE(s0, 1, 4, 0, 2 * kt + 3, 0)
    // phase 2: (kh1, mh0)  stages g=4kt+7 = B(2kt+3)
    PHASE(s1, 0, 0, 1, 2 * kt + 3, 1)
    // phase 3: (kh1, mh1)  stages g=4kt+8 = A(2kt+4)
    PHASE(s1, 1, 4, 0, 2 * kt + 4, 0)
#undef PHASE
  }

  // Epilogue: C/D layout col = lane&15, row = quad*4 + reg  [m89/m91]
  const int quad = lane >> 4;
  const int lr   = lane & 15;
  const int om = bm0 + wr * 128 + quad * 4;
  const int on = bn0 + wc * 64 + lr;
#pragma unroll
  for (int n = 0; n < 4; ++n) {
    float bv = bias[on + n * 16];
#pragma unroll
    for (int m = 0; m < 8; ++m) {
      f32x4 v = acc[m][n];
#pragma unroll
      for (int r = 0; r < 4; ++r) {
        C[(size_t)(om + m * 16 + r) * NDIM + (on + n * 16)] = v[r] + bv;
      }
    }
  }
}

extern "C" void kernel_launch(void* const* d_in, const int* in_sizes, int n_in,
                              void* d_out, int out_size, void* d_ws, size_t ws_size,
                              hipStream_t stream) {
  const float* x    = (const float*)d_in[0];  // 8192 x 4096
  const float* w    = (const float*)d_in[1];  // 4096 x 4096 ([k][n])
  const float* bias = (const float*)d_in[2];  // 4096
  float* out = (float*)d_out;

  unsigned short* Xbf = (unsigned short*)d_ws;  // 64 MB
  unsigned short* Wt  = (unsigned short*)((char*)d_ws + (size_t)MDIM * KDIM * 2);  // 32 MB

  prep_kernel<<<CVT_BLOCKS + 4096, 256, 0, stream>>>(x, w, Xbf, Wt);
  gemm_bf16_kernel<<<dim3((MDIM / BM) * (NDIM / BN)), 512, 0, stream>>>(Xbf, Wt, bias, out);
}

// Round 3
// 486.791 us; speedup vs baseline: 1.1409x; 1.0448x over previous
//
#include <hip/hip_runtime.h>

// Dense GEMM: C[M,N] = x[M,K] @ W[K,N] + bias[N], f32 in/out, bf16 MFMA compute.
// R6: (a) 1 barrier/phase, vmcnt(6) only at phases 1,3 placed BEFORE the
//     barrier (barrier publishes all waves' landed stages -> new-slot reads
//     safe; ring-4 slot reuse has 2 barriers of slack, so barrier2 removed).
//     (b) XCD mapping: 8 XCDs as 4(M)x2(N) regions of 8x8 wgs (2048^2 C) ->
//     A re-fetched 2x not 8x across XCDs.

#define MDIM 8192
#define NDIM 4096
#define KDIM 4096
#define BM 256
#define BN 256
#define BK 64
#define NKT (KDIM / BK)   // 64 K-tiles
#define NH  (KDIM / 32)   // 128 k-half tiles per operand

typedef __bf16 bf16x8 __attribute__((ext_vector_type(8)));
typedef float f32x4 __attribute__((ext_vector_type(4)));
typedef unsigned short u16x8 __attribute__((ext_vector_type(8)));

__device__ __forceinline__ unsigned short f32_to_bf16(float f) {
  union { float f; unsigned int u; } v; v.f = f;
  unsigned int r = 0x7FFFu + ((v.u >> 16) & 1u);  // round-to-nearest-even
  return (unsigned short)((v.u + r) >> 16);
}

// ---- fused pre-pass ------------------------------------------------------
#define CVT_BLOCKS 16384
__global__ __launch_bounds__(256) void prep_kernel(
    const float* __restrict__ x, const float* __restrict__ W,
    unsigned short* __restrict__ Xbf, unsigned short* __restrict__ Wt) {
  __shared__ __align__(16) unsigned short tile[64][72];

  const int bid = blockIdx.x;
  const int t = threadIdx.x;
  if (bid < CVT_BLOCKS) {
    const int i = (bid * 256 + t) * 8;
    float4 a = *(const float4*)(x + i);
    float4 b = *(const float4*)(x + i + 4);
    union { unsigned short s[8]; uint4 v; } o;
    o.s[0] = f32_to_bf16(a.x); o.s[1] = f32_to_bf16(a.y);
    o.s[2] = f32_to_bf16(a.z); o.s[3] = f32_to_bf16(a.w);
    o.s[4] = f32_to_bf16(b.x); o.s[5] = f32_to_bf16(b.y);
    o.s[6] = f32_to_bf16(b.z); o.s[7] = f32_to_bf16(b.w);
    *(uint4*)(Xbf + i) = o.v;
  } else {
    const int tb = bid - CVT_BLOCKS;      // 4096 blocks: 64 n-tiles x 64 k-tiles
    const int n0 = (tb & 63) * 64;
    const int k0 = (tb >> 6) * 64;
#pragma unroll
    for (int p = 0; p < 4; p++) {
      const int kk = p * 16 + (t >> 4);
      const int nl = (t & 15) * 4;
      float4 v = *(const float4*)(W + (size_t)(k0 + kk) * NDIM + n0 + nl);
      tile[nl + 0][kk] = f32_to_bf16(v.x);
      tile[nl + 1][kk] = f32_to_bf16(v.y);
      tile[nl + 2][kk] = f32_to_bf16(v.z);
      tile[nl + 3][kk] = f32_to_bf16(v.w);
    }
    __syncthreads();
#pragma unroll
    for (int q = 0; q < 2; q++) {
      const int nl = q * 32 + (t >> 3);
      const int kl = (t & 7) * 8;
      *(u16x8*)(Wt + (size_t)(n0 + nl) * KDIM + k0 + kl) =
          *(const u16x8*)(&tile[nl][kl]);
    }
  }
}

// ---- GEMM ---------------------------------------------------------------
#define GLD_TO_LDS(g, l)                                                      \
  __builtin_amdgcn_global_load_lds(                                           \
      (const __attribute__((address_space(1))) void*)(g),                     \
      (__attribute__((address_space(3))) void*)(l), 16, 0, 0)

__global__ __launch_bounds__(512, 2) void gemm_bf16_kernel(
    const unsigned short* __restrict__ A,   // M x K bf16
    const unsigned short* __restrict__ Bt,  // N x K bf16
    const float* __restrict__ bias,
    float* __restrict__ C) {
  // 4 ring slots per operand; slot = k-half tile [256 rows][32 k] bf16 (16 KB).
  // Within a row (64 B = 4 chunks of 16 B), LDS chunk c' holds global chunk
  // c = c' ^ ((row>>1)&3): ds_read_b128 lanes land 2/bank-cell (free).
  __shared__ __align__(16) unsigned short As[4 * 8192];  // 64 KB
  __shared__ __align__(16) unsigned short Bs[4 * 8192];  // 64 KB

  const int tid  = threadIdx.x;
  const int w    = tid >> 6;
  const int lane = tid & 63;

  // XCD mapping: xcd = bid&7 (round-robin dispatch). 8 XCDs arranged as
  // 4(M) x 2(N) regions; each region = 8bm x 8bn wgs = 2048x2048 of C.
  // -> A-row-panels re-fetched by 2 XCDs (not 8), B-col-panels by 4.
  const int xcd   = blockIdx.x & 7;
  const int local = blockIdx.x >> 3;               // 0..63
  const int bm0 = ((xcd >> 1) * 8 + (local & 7)) * BM;
  const int bn0 = ((xcd & 1) * 8 + (local >> 3)) * BN;

  // ---- staging map: wave w writes slot bytes [w*2KB, +2KB) as 2 x 1KB ----
  // linear LDS elem = w*1024 + j*512 + lane*8 -> row = w*32+j*16+(lane>>2),
  // chunk' = lane&3; source chunk = chunk' ^ ((row>>1)&3) = (lane&3)^((lane>>3)&3)
  const int stR = w * 32 + (lane >> 2);
  const int cSw = ((lane & 3) ^ ((lane >> 3) & 3)) * 8;
  const unsigned short* sA0 = A  + (size_t)(bm0 + stR) * KDIM + cSw;
  const unsigned short* sA1 = sA0 + (size_t)16 * KDIM;
  const unsigned short* sB0 = Bt + (size_t)(bn0 + stR) * KDIM + cSw;
  const unsigned short* sB1 = sB0 + (size_t)16 * KDIM;
  unsigned short* ldsA = As + w * 1024;   // + slot*8192 (+512 for j=1)
  unsigned short* ldsB = Bs + w * 1024;

  // ---- compute map: wave (wr,wc) owns 128x64 at (wr*128, wc*64) ----------
  const int wr = w >> 2;
  const int wc = w & 3;
  // frag read: lane row = base+(lane&15), k-chunk = lane>>4, swizzled:
  const int pa = (lane & 15) * 32 + (((lane >> 4) ^ ((lane >> 1) & 3))) * 8;
  const unsigned short* aBase = As + (wr * 128) * 32 + pa;  // +slot +mh*2048 +fm*512
  const unsigned short* bBase = Bs + (wc * 64) * 32 + pa;   // +slot +fn*512

  f32x4 acc[8][4] = {};

  // stage half-tile h of operand (0=A,1=B): exactly 2 vmem ops per wave.
  // Tail (h>=NH): re-stage k-half 0 into the (never-again-read) slot so the
  // per-phase vmcnt op count stays exact.
  auto stage = [&](int h, int isB) {
    const int koff = (h < NH) ? h * 32 : 0;
    const int sb = (h & 3) * 8192;
    if (isB) {
      GLD_TO_LDS(sB0 + koff, ldsB + sb);
      GLD_TO_LDS(sB1 + koff, ldsB + sb + 512);
    } else {
      GLD_TO_LDS(sA0 + koff, ldsA + sb);
      GLD_TO_LDS(sA1 + koff, ldsA + sb + 512);
    }
  };

  // Prologue: issue A(h0),B(h0),A(h1),B(h1),A(h2) = 10 ops; vmcnt(6) retires
  // the oldest 4 = A(h0)+B(h0); barrier publishes them to all waves.
  stage(0, 0); stage(0, 1); stage(1, 0); stage(1, 1); stage(2, 0);
  asm volatile("s_waitcnt vmcnt(6)" ::: "memory");
  __builtin_amdgcn_sched_barrier(0);
  __builtin_amdgcn_s_barrier();
  __builtin_amdgcn_sched_barrier(0);

  for (int kt = 0; kt < NKT; ++kt) {
    const int s0 = ((2 * kt) & 3) * 8192;
    const int s1 = ((2 * kt + 1) & 3) * 8192;
    bf16x8 aF[4], bF[4];

    // Phase: reads -> stage -> [vmcnt(6)] -> barrier -> lgkm(0) -> MFMA.
    // vmcnt BEFORE barrier: every wave confirms its own staged half-tiles
    // landed, then the barrier publishes them -> next phase's new-slot reads
    // are safe. Slot overwrite (stage h, old h-4) trails the old readers by
    // 2 full barriers (see R5 derivation), so no second barrier needed.
#define PHASE(SLOT, MH, ACC0, LOADB, STH, STB, DOVM)                          \
    {                                                                         \
      _Pragma("unroll")                                                       \
      for (int f = 0; f < 4; ++f)                                             \
        aF[f] = *(const bf16x8*)(aBase + (SLOT) + (MH)*2048 + f * 512);       \
      if (LOADB) {                                                            \
        _Pragma("unroll")                                                     \
        for (int f = 0; f < 4; ++f)                                           \
          bF[f] = *(const bf16x8*)(bBase + (SLOT) + f * 512);                 \
      }                                                                       \
      stage((STH), (STB));                                                    \
      if (DOVM) asm volatile("s_waitcnt vmcnt(6)" ::: "memory");              \
      __builtin_amdgcn_sched_barrier(0);                                      \
      __builtin_amdgcn_s_barrier();                                           \
      asm volatile("s_waitcnt lgkmcnt(0)" ::: "memory");                      \
      __builtin_amdgcn_sched_barrier(0);                                      \
      __builtin_amdgcn_s_setprio(1);                                          \
      _Pragma("unroll")                                                       \
      for (int m = 0; m < 4; ++m)                                             \
        _Pragma("unroll")                                                     \
        for (int n = 0; n < 4; ++n)                                           \
          acc[(ACC0) + m][n] = __builtin_amdgcn_mfma_f32_16x16x32_bf16(       \
              aF[m], bF[n], acc[(ACC0) + m][n], 0, 0, 0);                     \
      __builtin_amdgcn_s_setprio(0);                                          \
    }

    // phase 0: (kh0, mh0)  stages B(2kt+2)
    PHASE(s0, 0, 0, 1, 2 * kt + 2, 1, 0)
    // phase 1: (kh0, mh1)  stages A(2kt+3); vmcnt -> h(2kt+1) published
    PHASE(s0, 1, 4, 0, 2 * kt + 3, 0, 1)
    // phase 2: (kh1, mh0)  stages B(2kt+3)
    PHASE(s1, 0, 0, 1, 2 * kt + 3, 1, 0)
    // phase 3: (kh1, mh1)  stages A(2kt+4); vmcnt -> h(2kt+2) published
    PHASE(s1, 1, 4, 0, 2 * kt + 4, 0, 1)
#undef PHASE
  }

  // Epilogue: C/D layout col = lane&15, row = quad*4 + reg  [m89/m91]
  const int quad = lane >> 4;
  const int lr   = lane & 15;
  const int om = bm0 + wr * 128 + quad * 4;
  const int on = bn0 + wc * 64 + lr;
#pragma unroll
  for (int n = 0; n < 4; ++n) {
    float bv = bias[on + n * 16];
#pragma unroll
    for (int m = 0; m < 8; ++m) {
      f32x4 v = acc[m][n];
#pragma unroll
      for (int r = 0; r < 4; ++r) {
        C[(size_t)(om + m * 16 + r) * NDIM + (on + n * 16)] = v[r] + bv;
      }
    }
  }
}

extern "C" void kernel_launch(void* const* d_in, const int* in_sizes, int n_in,
                              void* d_out, int out_size, void* d_ws, size_t ws_size,
                              hipStream_t stream) {
  const float* x    = (const float*)d_in[0];  // 8192 x 4096
  const float* w    = (const float*)d_in[1];  // 4096 x 4096 ([k][n])
  const float* bias = (const float*)d_in[2];  // 4096
  float* out = (float*)d_out;

  unsigned short* Xbf = (unsigned short*)d_ws;  // 64 MB
  unsigned short* Wt  = (unsigned short*)((char*)d_ws + (size_t)MDIM * KDIM * 2);  // 32 MB

  prep_kernel<<<CVT_BLOCKS + 4096, 256, 0, stream>>>(x, w, Xbf, Wt);
  gemm_bf16_kernel<<<dim3((MDIM / BM) * (NDIM / BN)), 512, 0, stream>>>(Xbf, Wt, bias, out);
}